// Round 7
// baseline (177.552 us; speedup 1.0000x reference)
//
#include <hip/hip_runtime.h>
#include <cstdint>

#define NRAD 4096
#define NLID 16384
#define KMIX 8
#define TOPK 10
#define CF   16
#define LOG2PI 1.8378770664093453f
#define MAIN_BLOCKS 2048          // 2 rows/block, 2 waves/row
#define R2T 225u                  // tier-1 distance filter: d2 <= 225 (r=15)

static constexpr unsigned INF_D2 = 62851u;   // > max real d2 (40^2 + 2*175^2 = 62850)

// ---------------------------------------------------------------- helpers
__device__ __forceinline__ void insert_key(unsigned (&t)[TOPK], unsigned key) {
    // t ascending; branch-free exact insert of key into 10 smallest.
#pragma unroll
    for (int i = TOPK - 1; i >= 1; --i) {
        unsigned hi = key > t[i - 1] ? key : t[i - 1];
        t[i] = hi < t[i] ? hi : t[i];
    }
    t[0] = key < t[0] ? key : t[0];
}

__device__ __forceinline__ void merge10(unsigned (&t)[TOPK], int lane,
                                        unsigned& mine, unsigned& first, unsigned& tenth) {
#pragma unroll
    for (int r = 0; r < TOPK; ++r) {
        unsigned v = t[0];
#pragma unroll
        for (int off = 32; off >= 1; off >>= 1) {
            unsigned o = __shfl_xor(v, off, 64);
            v = o < v ? o : v;
        }
        if (t[0] == v) {                       // unique keys -> exactly one popper
#pragma unroll
            for (int i = 0; i < TOPK - 1; ++i) t[i] = t[i + 1];
            t[TOPK - 1] = 0xFFFFFFFFu;
        }
        if (lane == r) mine = v;
        if (r == 0) first = v;
        if (r == TOPK - 1) tenth = v;
    }
}

__device__ __forceinline__ float waveReduceSum(float v) {
#pragma unroll
    for (int off = 32; off >= 1; off >>= 1) v += __shfl_down(v, off, 64);
    return v;
}

// ---------------------------------------------------------------- prep
__global__ __launch_bounds__(256) void prep_kernel(
        const int* __restrict__ lidar_indices,
        unsigned* __restrict__ packed_full,
        uint2* __restrict__ compacted,
        int* __restrict__ cursor) {           // [4], pre-zeroed
    int i = blockIdx.x * 256 + threadIdx.x;
    int lane = threadIdx.x & 63;
    int4 li = ((const int4*)lidar_indices)[i];
    int b = li.x;
    unsigned pos = ((unsigned)li.y << 16) | ((unsigned)li.z << 8) | (unsigned)li.w;
    packed_full[i] = ((unsigned)b << 22) | pos;
#pragma unroll
    for (int b2 = 0; b2 < 4; ++b2) {
        unsigned long long mask = __ballot(b == b2);
        if (b == b2) {
            int leader = __ffsll(mask) - 1;
            int off = (int)__popcll(mask & ((1ull << lane) - 1ull));
            int s = 0;
            if (lane == leader) s = atomicAdd(&cursor[b2], (int)__popcll(mask));
            s = __shfl(s, leader, 64);
            compacted[b2 * NLID + s + off] = make_uint2(pos, (unsigned)i);
        }
    }
}

// ---------------------------------------------------------------- main
// 2048 blocks x 4 waves. Each block: 2 rows; each row: 2 waves scanning
// interleaved halves with a d2<=R2T filter; per-wave top-10 -> LDS ->
// leader-wave 20-key tournament. Sentinel tenth => exact unfiltered rescan
// (then cross-batch scan if the row's batch has <10 lidar). Leader lanes
// 0..9 compute MDN/occ/int in-wave. Block partials + done-counter final.
__global__ __launch_bounds__(256) void main_kernel(
        const float* __restrict__ mu_off, const float* __restrict__ log_sig_off,
        const float* __restrict__ mu_int, const float* __restrict__ occ_logit,
        const float* __restrict__ mix_logit, const float* __restrict__ lidar_features,
        const int* __restrict__ radar_indices, const int* __restrict__ lidar_indices,
        const uint2* __restrict__ compacted, const unsigned* __restrict__ packed_full,
        const int* __restrict__ cursor, float4* __restrict__ partials,
        unsigned* __restrict__ dctr, float* __restrict__ out) {
    int tid = threadIdx.x, lane = tid & 63, wid = tid >> 6;
    int half = wid & 1;                        // which half of the candidates
    int row  = blockIdx.x * 2 + (wid >> 1);

    int4 ri = ((const int4*)radar_indices)[row];
    int rb = ri.x, rz = ri.y, ry = ri.z, rx = ri.w;
    int c_cnt = cursor[rb];

    unsigned t[TOPK];
#pragma unroll
    for (int i = 0; i < TOPK; ++i) t[i] = 0xFFFFFFFFu;

    // ---- tier-1: filtered scan of this wave's half (it = half, half+2, ...)
    const uint4* src = (const uint4*)(compacted + rb * NLID);
    int iters = (c_cnt + 127) >> 7;
    uint4 q = src[half * 64 + lane];           // always in-region (half<2)
    for (int it = half; it < iters; it += 2) {
        uint4 qn = src[(it + 2) * 64 + lane];  // unguarded: bounded ws overrun, masked
        int c0 = (it * 64 + lane) * 2;
        {
            int dz = (int)((q.x >> 16) & 63u)  - rz;
            int dy = (int)((q.x >> 8)  & 255u) - ry;
            int dx = (int)(q.x & 255u)         - rx;
            unsigned d2 = (unsigned)(dz * dz + dy * dy + dx * dx);
            if (d2 <= R2T && c0 < c_cnt) insert_key(t, (d2 << 14) | q.y);
        }
        {
            int dz = (int)((q.z >> 16) & 63u)  - rz;
            int dy = (int)((q.z >> 8)  & 255u) - ry;
            int dx = (int)(q.z & 255u)         - rx;
            unsigned d2 = (unsigned)(dz * dz + dy * dy + dx * dx);
            if (d2 <= R2T && c0 + 1 < c_cnt) insert_key(t, (d2 << 14) | q.w);
        }
        q = qn;
    }

    unsigned mine = 0, first = 0, tenth = 0;
    merge10(t, lane, mine, first, tenth);

    __shared__ unsigned pairbuf[4][16];
    if (lane < TOPK) pairbuf[wid][lane] = mine;
    __syncthreads();

    // ---- leader waves (half==0) merge the pair + handle fallbacks + MDN
    float lp = 0.f, ip = 0.f, oc = 0.f, mc = 0.f;
    if (half == 0) {
        unsigned k = 0xFFFFFFFFu;
        if (lane < TOPK)           k = pairbuf[wid][lane];
        else if (lane < 2 * TOPK)  k = pairbuf[wid + 1][lane - TOPK];
        unsigned fin = 0xFFFFFFFFu;
        first = 0xFFFFFFFFu; tenth = 0xFFFFFFFFu;
#pragma unroll
        for (int r = 0; r < TOPK; ++r) {
            unsigned v = k;
#pragma unroll
            for (int off = 32; off >= 1; off >>= 1) {
                unsigned o = __shfl_xor(v, off, 64);
                v = o < v ? o : v;
            }
            if (k == v) k = 0xFFFFFFFFu;       // pop (dup sentinels harmless)
            if (lane == r) fin = v;
            if (r == 0) first = v;
            if (r == TOPK - 1) tenth = v;
        }
        bool matched = true;

        if (tenth == 0xFFFFFFFFu) {
            // tier-2: full same-batch unfiltered scan (exact), leader wave only
#pragma unroll
            for (int i = 0; i < TOPK; ++i) t[i] = 0xFFFFFFFFu;
            uint4 q0 = src[lane];
            for (int it = 0; it < iters; ++it) {
                uint4 qn2 = src[(it + 1) * 64 + lane];
                int c0 = (it * 64 + lane) * 2;
                {
                    int dz = (int)((q0.x >> 16) & 63u)  - rz;
                    int dy = (int)((q0.x >> 8)  & 255u) - ry;
                    int dx = (int)(q0.x & 255u)         - rx;
                    unsigned d2 = (unsigned)(dz * dz + dy * dy + dx * dx);
                    unsigned key = (c0 < c_cnt) ? ((d2 << 14) | q0.y) : 0xFFFFFFFFu;
                    insert_key(t, key);
                }
                {
                    int dz = (int)((q0.z >> 16) & 63u)  - rz;
                    int dy = (int)((q0.z >> 8)  & 255u) - ry;
                    int dx = (int)(q0.z & 255u)         - rx;
                    unsigned d2 = (unsigned)(dz * dz + dy * dy + dx * dx);
                    unsigned key = (c0 + 1 < c_cnt) ? ((d2 << 14) | q0.w) : 0xFFFFFFFFu;
                    insert_key(t, key);
                }
                q0 = qn2;
            }
            merge10(t, lane, fin, first, tenth);

            if (tenth == 0xFFFFFFFFu) {
                // tier-3: row's batch has <10 lidar: cross-batch scan, INF keys
#pragma unroll
                for (int i = 0; i < TOPK; ++i) t[i] = 0xFFFFFFFFu;
                for (int it = 0; it < NLID / 256; ++it) {
                    uint4 p4 = ((const uint4*)packed_full)[it * 64 + lane];
                    unsigned base = it * 256 + lane * 4;
                    unsigned ps[4] = {p4.x, p4.y, p4.z, p4.w};
#pragma unroll
                    for (int j = 0; j < 4; ++j) {
                        unsigned p = ps[j];
                        int b  = (int)(p >> 22);
                        int dz = (int)((p >> 16) & 63u)  - rz;
                        int dy = (int)((p >> 8)  & 255u) - ry;
                        int dx = (int)(p & 255u)         - rx;
                        unsigned d2 = (unsigned)(dz * dz + dy * dy + dx * dx);
                        unsigned hi = (b == rb) ? d2 : INF_D2;
                        insert_key(t, (hi << 14) | (base + j));
                    }
                }
                merge10(t, lane, fin, first, tenth);
                matched = first < (INF_D2 << 14);
            }
        }

        // ---- MDN/occ/int: lanes 0..9 handle (row, lane); loads broadcast
        float mf = matched ? 1.f : 0.f;
        if (lane < TOPK) {
            int nni = (int)(fin & 0x3FFFu);
            int4 ll = ((const int4*)lidar_indices)[nni];
            float y0 = mf * (float)(ll.w - rx);
            float y1 = mf * (float)(ll.z - ry);
            float y2 = mf * (float)(ll.y - rz);

            float mix[KMIX];
            float mmax = -1e30f;
#pragma unroll
            for (int kk = 0; kk < KMIX; ++kk) {
                mix[kk] = mix_logit[row * KMIX + kk];
                mmax = fmaxf(mmax, mix[kk]);
            }
            float msum = 0.f;
#pragma unroll
            for (int kk = 0; kk < KMIX; ++kk) msum += __expf(mix[kk] - mmax);
            float logZ = mmax + __logf(msum);

            float lpost[KMIX];
            float pmax = -1e30f;
#pragma unroll
            for (int kk = 0; kk < KMIX; ++kk) {
                int bidx = (row * KMIX + kk) * 3;
                float mu0 = mu_off[bidx + 0], mu1 = mu_off[bidx + 1], mu2 = mu_off[bidx + 2];
                float l0 = log_sig_off[bidx + 0], l1 = log_sig_off[bidx + 1], l2 = log_sig_off[bidx + 2];
                float s0 = __expf(2.f * l0) + 1e-12f;
                float s1 = __expf(2.f * l1) + 1e-12f;
                float s2 = __expf(2.f * l2) + 1e-12f;
                float d0 = y0 - mu0, d1 = y1 - mu1, d2v = y2 - mu2;
                float qq = d0 * d0 / s0 + d1 * d1 / s1 + d2v * d2v / s2
                         + 2.f * (l0 + l1 + l2) + 3.f * LOG2PI;
                lpost[kk] = -0.5f * qq + (mix[kk] - logZ);
                pmax = fmaxf(pmax, lpost[kk]);
            }
            float ex[KMIX];
            float se = 0.f;
#pragma unroll
            for (int kk = 0; kk < KMIX; ++kk) { ex[kk] = __expf(lpost[kk] - pmax); se += ex[kk]; }
            float logp = pmax + __logf(se);

            float gt = 0.f;
            if (matched) {
                const float* lf = lidar_features + nni * CF;
                gt = 0.25f * (lf[3] + lf[7] + lf[11] + lf[15]);
            }
            float inv_se = 1.f / se;
            float isum = 0.f;
#pragma unroll
            for (int kk = 0; kk < KMIX; ++kk)
                isum += ex[kk] * inv_se * fabsf(mu_int[row * KMIX + kk] - gt);

            lp = mf * logp;
            ip = mf * isum;
            if (lane == 0) {
                float oa = -1e30f;
#pragma unroll
                for (int kk = 0; kk < KMIX; ++kk) oa = fmaxf(oa, occ_logit[row * KMIX + kk]);
                float soft_abs = log1pf(__expf(-fabsf(oa)));
                oc = mf * (soft_abs + fmaxf(-oa, 0.f)) + (1.f - mf) * (soft_abs + fmaxf(oa, 0.f));
                mc = mf;
            }
        }
    }

    // ---- block partial, done-counter, last-block finalize
    lp = waveReduceSum(lp); ip = waveReduceSum(ip);
    oc = waveReduceSum(oc); mc = waveReduceSum(mc);
    __shared__ float sA[4], sB[4], sC[4], sD[4];
    __shared__ int isLast;
    if (lane == 0) { sA[wid] = lp; sB[wid] = ip; sC[wid] = oc; sD[wid] = mc; }
    __syncthreads();
    if (tid == 0) {
        partials[blockIdx.x] = make_float4(sA[0] + sA[1] + sA[2] + sA[3],
                                           sB[0] + sB[1] + sB[2] + sB[3],
                                           sC[0] + sC[1] + sC[2] + sC[3],
                                           sD[0] + sD[1] + sD[2] + sD[3]);
        __threadfence();
        unsigned done = atomicAdd(dctr, 1u);
        isLast = (done == (unsigned)(MAIN_BLOCKS - 1)) ? 1 : 0;
    }
    __syncthreads();
    if (isLast) {
        __threadfence();   // acquire: other blocks' partials visible
        float a = 0.f, b = 0.f, c = 0.f, d = 0.f;
        for (int i = tid; i < MAIN_BLOCKS; i += 256) {
            float4 p = partials[i];
            a += p.x; b += p.y; c += p.z; d += p.w;
        }
        a = waveReduceSum(a); b = waveReduceSum(b);
        c = waveReduceSum(c); d = waveReduceSum(d);
        if (lane == 0) { sA[wid] = a; sB[wid] = b; sC[wid] = c; sD[wid] = d; }
        __syncthreads();
        if (tid == 0) {
            a = sA[0] + sA[1] + sA[2] + sA[3];
            b = sB[0] + sB[1] + sB[2] + sB[3];
            c = sC[0] + sC[1] + sC[2] + sC[3];
            d = sD[0] + sD[1] + sD[2] + sD[3];
            float occ_loss = c / (float)NRAD;
            float mdn_nll  = -a / (d * (float)TOPK);
            float int_loss = b / (d * (float)TOPK * (float)KMIX);
            out[0] = 0.2f * occ_loss + mdn_nll + 0.1f * int_loss;
        }
    }
}

// ---------------------------------------------------------------- launch
extern "C" void kernel_launch(void* const* d_in, const int* in_sizes, int n_in,
                              void* d_out, int out_size, void* d_ws, size_t ws_size,
                              hipStream_t stream) {
    const float* mu_off         = (const float*)d_in[0];
    const float* log_sig_off    = (const float*)d_in[1];
    const float* mu_int         = (const float*)d_in[2];
    const float* occ_logit      = (const float*)d_in[3];
    const float* mix_logit      = (const float*)d_in[4];
    const float* lidar_features = (const float*)d_in[5];
    const int*   radar_indices  = (const int*)d_in[6];
    const int*   lidar_indices  = (const int*)d_in[7];
    float* out = (float*)d_out;

    char* ws = (char*)d_ws;
    unsigned* packed_full = (unsigned*)(ws + 0);         //  64 KB
    uint2*    compacted   = (uint2*)(ws + 65536);        //  4*16384*8 = 512 KB
    int*      cursor      = (int*)(ws + 589824);         //  16 B
    unsigned* dctr        = (unsigned*)(ws + 589840);    //  4 B
    float4*   partials    = (float4*)(ws + 589888);      //  2048*16 = 32 KB

    hipMemsetAsync(ws + 589824, 0, 64, stream);          // cursor + dctr

    hipLaunchKernelGGL(prep_kernel, dim3(NLID / 256), dim3(256), 0, stream,
                       lidar_indices, packed_full, compacted, cursor);
    hipLaunchKernelGGL(main_kernel, dim3(MAIN_BLOCKS), dim3(256), 0, stream,
                       mu_off, log_sig_off, mu_int, occ_logit, mix_logit,
                       lidar_features, radar_indices, lidar_indices,
                       compacted, packed_full, cursor, partials, dctr, out);
}

// Round 8
// 131.136 us; speedup vs baseline: 1.3539x; 1.3539x over previous
//
#include <hip/hip_runtime.h>
#include <cstdint>

#define NRAD 4096
#define NLID 16384
#define KMIX 8
#define TOPK 10
#define CF   16
#define LOG2PI 1.8378770664093453f
#define MAIN_BLOCKS 1024          // 4 rows/block, 1 wave/row (R6 skeleton)
#define NCELL 363                 // 3 z-cells x 11 y-cells x 11 x-cells (size 16)
#define CAP   21                  // slots/cell; 3 x-cells * 21 = 63 lanes
#define R2T   225u                // filter radius^2; cell 16 => outside d2 >= 256

static constexpr unsigned INF_D2 = 62851u;   // > max real d2 (40^2 + 2*175^2 = 62850)

// ---------------------------------------------------------------- helpers
__device__ __forceinline__ void insert_key(unsigned (&t)[TOPK], unsigned key) {
    // t ascending; branch-free exact insert of key into 10 smallest.
#pragma unroll
    for (int i = TOPK - 1; i >= 1; --i) {
        unsigned hi = key > t[i - 1] ? key : t[i - 1];
        t[i] = hi < t[i] ? hi : t[i];
    }
    t[0] = key < t[0] ? key : t[0];
}

__device__ __forceinline__ void merge10(unsigned (&t)[TOPK], int lane,
                                        unsigned& mine, unsigned& first, unsigned& tenth) {
#pragma unroll
    for (int r = 0; r < TOPK; ++r) {
        unsigned v = t[0];
#pragma unroll
        for (int off = 32; off >= 1; off >>= 1) {
            unsigned o = __shfl_xor(v, off, 64);
            v = o < v ? o : v;
        }
        if (t[0] == v) {                       // unique keys -> exactly one popper
#pragma unroll
            for (int i = 0; i < TOPK - 1; ++i) t[i] = t[i + 1];
            t[TOPK - 1] = 0xFFFFFFFFu;
        }
        if (lane == r) mine = v;
        if (r == 0) first = v;
        if (r == TOPK - 1) tenth = v;
    }
}

__device__ __forceinline__ float waveReduceSum(float v) {
#pragma unroll
    for (int off = 32; off >= 1; off >>= 1) v += __shfl_down(v, off, 64);
    return v;
}

// ---------------------------------------------------------------- prep
// 64 blocks: pack positions; scatter each lidar into (a) its batch's compacted
// region (for fallback scans) and (b) its spatial cell (cap 21; overflow
// detected via cnt>CAP at query time). Scatter order nondeterministic == fine.
__global__ __launch_bounds__(256) void prep_kernel(
        const int* __restrict__ lidar_indices,
        unsigned* __restrict__ packed_full,
        uint2* __restrict__ compacted,
        uint2* __restrict__ cells,
        int* __restrict__ cellcnt,            // [4*NCELL], pre-zeroed
        int* __restrict__ cursor) {           // [4], pre-zeroed
    int i = blockIdx.x * 256 + threadIdx.x;
    int lane = threadIdx.x & 63;
    int4 li = ((const int4*)lidar_indices)[i];
    int b = li.x;
    unsigned pos = ((unsigned)li.y << 16) | ((unsigned)li.z << 8) | (unsigned)li.w;
    packed_full[i] = ((unsigned)b << 22) | pos;

    // spatial cell
    int g = b * NCELL + (li.y >> 4) * 121 + (li.z >> 4) * 11 + (li.w >> 4);
    int slot = atomicAdd(&cellcnt[g], 1);
    if (slot < CAP) cells[g * CAP + slot] = make_uint2(pos, (unsigned)i);

    // batch-compacted (fallback path)
#pragma unroll
    for (int b2 = 0; b2 < 4; ++b2) {
        unsigned long long mask = __ballot(b == b2);
        if (b == b2) {
            int leader = __ffsll(mask) - 1;
            int off = (int)__popcll(mask & ((1ull << lane) - 1ull));
            int s = 0;
            if (lane == leader) s = atomicAdd(&cursor[b2], (int)__popcll(mask));
            s = __shfl(s, leader, 64);
            compacted[b2 * NLID + s + off] = make_uint2(pos, (unsigned)i);
        }
    }
}

// ---------------------------------------------------------------- main
// 1024 blocks x 4 waves; one radar row per wave. Cell scan: 9 unrolled
// (z,y)-neighbor rounds; lanes 0..62 = 3 x-cells x 21 slots. Keys with
// d2<=225 only (exact: points outside 27 cells have d2>=256). Fallback to
// full same-batch scan if <10 pass or any neighbor cell overflowed; then
// cross-batch scan if the batch has <10 lidar. MDN in-wave (lanes 0..9).
__global__ __launch_bounds__(256) void main_kernel(
        const float* __restrict__ mu_off, const float* __restrict__ log_sig_off,
        const float* __restrict__ mu_int, const float* __restrict__ occ_logit,
        const float* __restrict__ mix_logit, const float* __restrict__ lidar_features,
        const int* __restrict__ radar_indices, const int* __restrict__ lidar_indices,
        const uint2* __restrict__ compacted, const unsigned* __restrict__ packed_full,
        const uint2* __restrict__ cells, const int* __restrict__ cellcnt,
        const int* __restrict__ cursor, float4* __restrict__ partials,
        unsigned* __restrict__ dctr, float* __restrict__ out) {
    int tid = threadIdx.x, lane = tid & 63, wid = tid >> 6;
    int row = blockIdx.x * 4 + wid;

    int4 ri = ((const int4*)radar_indices)[row];
    int rb = ri.x, rz = ri.y, ry = ri.z, rx = ri.w;
    int cz = rz >> 4, cy = ry >> 4, cx = rx >> 4;

    unsigned t[TOPK];
#pragma unroll
    for (int i = 0; i < TOPK; ++i) t[i] = 0xFFFFFFFFu;

    // lane -> (x-cell j in {-1,0,+1}, slot)
    int j    = lane / CAP;             // 0..2 (lane 63 -> 3, masked)
    int slot = lane - j * CAP;
    int xc   = cx - 1 + j;
    bool lane_ok = (lane < 63) && ((unsigned)xc <= 10u);
    bool needs_fb = false;

#pragma unroll
    for (int dzy = 0; dzy < 9; ++dzy) {
        int zc = cz + (dzy / 3) - 1;
        int yc = cy + (dzy % 3) - 1;
        bool cellok = lane_ok && ((unsigned)zc <= 2u) && ((unsigned)yc <= 10u);
        int g = rb * NCELL + zc * 121 + yc * 11 + xc;   // may be OOB when !cellok (ws-bounded, masked)
        int n = cellcnt[g];                             // speculative; masked by cellok
        uint2 c = cells[g * CAP + slot];                // speculative; masked by slot<n
        needs_fb |= cellok && (n > CAP);
        bool active = cellok && (slot < n);
        int dz = (int)((c.x >> 16) & 63u)  - rz;
        int dy = (int)((c.x >> 8)  & 255u) - ry;
        int dx = (int)(c.x & 255u)         - rx;
        unsigned d2 = (unsigned)(dz * dz + dy * dy + dx * dx);
        if (active && d2 <= R2T) insert_key(t, (d2 << 14) | c.y);
    }

    unsigned mine = 0, first = 0, tenth = 0;
    merge10(t, lane, mine, first, tenth);
    bool matched = true;
    bool fb = (__ballot(needs_fb) != 0ull) || (tenth == 0xFFFFFFFFu);

    if (fb) {
        // full same-batch scan (exact), 2-deep prefetch
        int c_cnt = cursor[rb];
        const uint4* src = (const uint4*)(compacted + rb * NLID);
        int iters = (c_cnt + 127) >> 7;
#pragma unroll
        for (int i = 0; i < TOPK; ++i) t[i] = 0xFFFFFFFFu;
        uint4 q0 = src[lane];
        uint4 q1 = src[64 + lane];
        for (int it = 0; it < iters; ++it) {
            uint4 qn = src[(it + 2) * 64 + lane];   // bounded ws overrun, masked
            int c0 = (it * 64 + lane) * 2;
            {
                int dz = (int)((q0.x >> 16) & 63u)  - rz;
                int dy = (int)((q0.x >> 8)  & 255u) - ry;
                int dx = (int)(q0.x & 255u)         - rx;
                unsigned d2 = (unsigned)(dz * dz + dy * dy + dx * dx);
                unsigned key = (c0 < c_cnt) ? ((d2 << 14) | q0.y) : 0xFFFFFFFFu;
                if (key < t[TOPK - 1]) insert_key(t, key);
            }
            {
                int dz = (int)((q0.z >> 16) & 63u)  - rz;
                int dy = (int)((q0.z >> 8)  & 255u) - ry;
                int dx = (int)(q0.z & 255u)         - rx;
                unsigned d2 = (unsigned)(dz * dz + dy * dy + dx * dx);
                unsigned key = (c0 + 1 < c_cnt) ? ((d2 << 14) | q0.w) : 0xFFFFFFFFu;
                if (key < t[TOPK - 1]) insert_key(t, key);
            }
            q0 = q1; q1 = qn;
        }
        merge10(t, lane, mine, first, tenth);

        if (tenth == 0xFFFFFFFFu) {
            // batch has <10 lidar: cross-batch scan with INF keys (exact tie-break)
#pragma unroll
            for (int i = 0; i < TOPK; ++i) t[i] = 0xFFFFFFFFu;
            for (int it = 0; it < NLID / 256; ++it) {
                uint4 p4 = ((const uint4*)packed_full)[it * 64 + lane];
                unsigned base = it * 256 + lane * 4;
                unsigned ps[4] = {p4.x, p4.y, p4.z, p4.w};
#pragma unroll
                for (int jj = 0; jj < 4; ++jj) {
                    unsigned p = ps[jj];
                    int b  = (int)(p >> 22);
                    int dz = (int)((p >> 16) & 63u)  - rz;
                    int dy = (int)((p >> 8)  & 255u) - ry;
                    int dx = (int)(p & 255u)         - rx;
                    unsigned d2 = (unsigned)(dz * dz + dy * dy + dx * dx);
                    unsigned hi = (b == rb) ? d2 : INF_D2;
                    insert_key(t, (hi << 14) | (base + jj));
                }
            }
            merge10(t, lane, mine, first, tenth);
            matched = first < (INF_D2 << 14);
        }
    }

    // ---- per-wave MDN/occ/int: lanes 0..9 handle (row, lane); loads broadcast
    float mf = matched ? 1.f : 0.f;
    float lp = 0.f, ip = 0.f, oc = 0.f, mc = 0.f;
    if (lane < TOPK) {
        int nni = (int)(mine & 0x3FFFu);
        int4 ll = ((const int4*)lidar_indices)[nni];
        float y0 = mf * (float)(ll.w - rx);
        float y1 = mf * (float)(ll.z - ry);
        float y2 = mf * (float)(ll.y - rz);

        float mix[KMIX];
        float mmax = -1e30f;
#pragma unroll
        for (int k = 0; k < KMIX; ++k) {
            mix[k] = mix_logit[row * KMIX + k];
            mmax = fmaxf(mmax, mix[k]);
        }
        float msum = 0.f;
#pragma unroll
        for (int k = 0; k < KMIX; ++k) msum += __expf(mix[k] - mmax);
        float logZ = mmax + __logf(msum);

        float lpost[KMIX];
        float pmax = -1e30f;
#pragma unroll
        for (int k = 0; k < KMIX; ++k) {
            int bidx = (row * KMIX + k) * 3;
            float mu0 = mu_off[bidx + 0], mu1 = mu_off[bidx + 1], mu2 = mu_off[bidx + 2];
            float l0 = log_sig_off[bidx + 0], l1 = log_sig_off[bidx + 1], l2 = log_sig_off[bidx + 2];
            float s0 = __expf(2.f * l0) + 1e-12f;
            float s1 = __expf(2.f * l1) + 1e-12f;
            float s2 = __expf(2.f * l2) + 1e-12f;
            float d0 = y0 - mu0, d1 = y1 - mu1, d2v = y2 - mu2;
            float qq = d0 * d0 / s0 + d1 * d1 / s1 + d2v * d2v / s2
                     + 2.f * (l0 + l1 + l2) + 3.f * LOG2PI;
            lpost[k] = -0.5f * qq + (mix[k] - logZ);
            pmax = fmaxf(pmax, lpost[k]);
        }
        float ex[KMIX];
        float se = 0.f;
#pragma unroll
        for (int k = 0; k < KMIX; ++k) { ex[k] = __expf(lpost[k] - pmax); se += ex[k]; }
        float logp = pmax + __logf(se);

        float gt = 0.f;
        if (matched) {
            const float* lf = lidar_features + nni * CF;
            gt = 0.25f * (lf[3] + lf[7] + lf[11] + lf[15]);
        }
        float inv_se = 1.f / se;
        float isum = 0.f;
#pragma unroll
        for (int k = 0; k < KMIX; ++k)
            isum += ex[k] * inv_se * fabsf(mu_int[row * KMIX + k] - gt);

        lp = mf * logp;
        ip = mf * isum;
        if (lane == 0) {
            float oa = -1e30f;
#pragma unroll
            for (int k = 0; k < KMIX; ++k) oa = fmaxf(oa, occ_logit[row * KMIX + k]);
            float soft_abs = log1pf(__expf(-fabsf(oa)));
            oc = mf * (soft_abs + fmaxf(-oa, 0.f)) + (1.f - mf) * (soft_abs + fmaxf(oa, 0.f));
            mc = mf;
        }
    }

    // ---- block partial, done-counter, last-block finalize
    lp = waveReduceSum(lp); ip = waveReduceSum(ip);
    oc = waveReduceSum(oc); mc = waveReduceSum(mc);
    __shared__ float sA[4], sB[4], sC[4], sD[4];
    __shared__ int isLast;
    if (lane == 0) { sA[wid] = lp; sB[wid] = ip; sC[wid] = oc; sD[wid] = mc; }
    __syncthreads();
    if (tid == 0) {
        partials[blockIdx.x] = make_float4(sA[0] + sA[1] + sA[2] + sA[3],
                                           sB[0] + sB[1] + sB[2] + sB[3],
                                           sC[0] + sC[1] + sC[2] + sC[3],
                                           sD[0] + sD[1] + sD[2] + sD[3]);
        __threadfence();
        unsigned done = atomicAdd(dctr, 1u);
        isLast = (done == (unsigned)(MAIN_BLOCKS - 1)) ? 1 : 0;
    }
    __syncthreads();
    if (isLast) {
        __threadfence();   // acquire: other blocks' partials visible
        float a = 0.f, b = 0.f, c = 0.f, d = 0.f;
        for (int i = tid; i < MAIN_BLOCKS; i += 256) {
            float4 p = partials[i];
            a += p.x; b += p.y; c += p.z; d += p.w;
        }
        a = waveReduceSum(a); b = waveReduceSum(b);
        c = waveReduceSum(c); d = waveReduceSum(d);
        if (lane == 0) { sA[wid] = a; sB[wid] = b; sC[wid] = c; sD[wid] = d; }
        __syncthreads();
        if (tid == 0) {
            a = sA[0] + sA[1] + sA[2] + sA[3];
            b = sB[0] + sB[1] + sB[2] + sB[3];
            c = sC[0] + sC[1] + sC[2] + sC[3];
            d = sD[0] + sD[1] + sD[2] + sD[3];
            float occ_loss = c / (float)NRAD;
            float mdn_nll  = -a / (d * (float)TOPK);
            float int_loss = b / (d * (float)TOPK * (float)KMIX);
            out[0] = 0.2f * occ_loss + mdn_nll + 0.1f * int_loss;
        }
    }
}

// ---------------------------------------------------------------- launch
extern "C" void kernel_launch(void* const* d_in, const int* in_sizes, int n_in,
                              void* d_out, int out_size, void* d_ws, size_t ws_size,
                              hipStream_t stream) {
    const float* mu_off         = (const float*)d_in[0];
    const float* log_sig_off    = (const float*)d_in[1];
    const float* mu_int         = (const float*)d_in[2];
    const float* occ_logit      = (const float*)d_in[3];
    const float* mix_logit      = (const float*)d_in[4];
    const float* lidar_features = (const float*)d_in[5];
    const int*   radar_indices  = (const int*)d_in[6];
    const int*   lidar_indices  = (const int*)d_in[7];
    float* out = (float*)d_out;

    char* ws = (char*)d_ws;
    unsigned* packed_full = (unsigned*)(ws + 0);          //  64 KB
    uint2*    compacted   = (uint2*)(ws + 65536);         //  4*16384*8 = 512 KB
    uint2*    cells       = (uint2*)(ws + 589824);        //  4*363*21*8 = 243936 B
    int*      cellcnt     = (int*)(ws + 834560);          //  4*363*4 = 5808 B
    int*      cursor      = (int*)(ws + 840368);          //  16 B
    unsigned* dctr        = (unsigned*)(ws + 840384);     //  4 B
    float4*   partials    = (float4*)(ws + 840448);       //  1024*16 = 16 KB

    // zero cellcnt + cursor + dctr in one contiguous memset
    hipMemsetAsync(ws + 834560, 0, 5888, stream);

    hipLaunchKernelGGL(prep_kernel, dim3(NLID / 256), dim3(256), 0, stream,
                       lidar_indices, packed_full, compacted, cells, cellcnt, cursor);
    hipLaunchKernelGGL(main_kernel, dim3(MAIN_BLOCKS), dim3(256), 0, stream,
                       mu_off, log_sig_off, mu_int, occ_logit, mix_logit,
                       lidar_features, radar_indices, lidar_indices,
                       compacted, packed_full, cells, cellcnt, cursor,
                       partials, dctr, out);
}